// Round 1
// baseline (222.086 us; speedup 1.0000x reference)
//
#include <hip/hip_runtime.h>
#include <float.h>

typedef __bf16 bf16x8 __attribute__((ext_vector_type(8)));
typedef __bf16 bf16x4 __attribute__((ext_vector_type(4)));
typedef float  f32x4  __attribute__((ext_vector_type(4)));

#define G      256
#define MT     32      // points per tile
#define H1DIM  64
#define H2DIM  128
#define LAT    256
#define H1PAD  72      // 144 B rows: 16B-aligned, 36 dw == 4 mod 32 -> 2-way (free) b128
#define H2PAD  136     // 272 B rows: 16B-aligned, 68 dw == 4 mod 32 -> 2-way (free) b128

// order-preserving float->uint map: max on uints == max on floats
__device__ __forceinline__ unsigned mapf(float f) {
  unsigned u = __float_as_uint(f);
  return (u & 0x80000000u) ? ~u : (u | 0x80000000u);
}
__device__ __forceinline__ float unmapf(unsigned u) {
  return (u & 0x80000000u) ? __uint_as_float(u & 0x7fffffffu) : __uint_as_float(~u);
}

// flush helper: vectors passed BY VALUE (no address-taken on caller arrays).
// Reduces over the 16 point-lanes, adds bias, atomicMax to global pooled[s].
// 8-wave version: wave owns 32 latent features (mt=2).
__device__ __forceinline__ void flush2(f32x4 v0, f32x4 v1,
                                       int s, int w, int q, int nn,
                                       const float* __restrict__ b3,
                                       unsigned* __restrict__ pooled) {
  f32x4 vv[2] = {v0, v1};
  #pragma unroll
  for (int mt = 0; mt < 2; ++mt)
    #pragma unroll
    for (int r = 0; r < 4; ++r) {
      int feat = w * 32 + mt * 16 + q * 4 + r;
      float v = vv[mt][r] + b3[feat];
      v = fmaxf(v, __shfl_xor(v, 1));
      v = fmaxf(v, __shfl_xor(v, 2));
      v = fmaxf(v, __shfl_xor(v, 4));
      v = fmaxf(v, __shfl_xor(v, 8));
      if (nn == 0) atomicMax(&pooled[s * LAT + feat], mapf(v));
    }
}

// ---------------- fused centroid + MLP + segment max ----------------
// 512 thr = 8 waves (was 4). Rationale: 4-wave version held 84 VGPR of weight
// fragments + ~64 acc regs per wave -> ~176 total -> 2 waves/SIMD occupancy cap
// (17% measured, latency-bound at MfmaUtil 22%). Splitting features 8 ways
// halves weights (w3f 64->32) AND accumulators (acc3 32->16, run 16->8):
// ~105 regs/wave fits __launch_bounds__(512,4) 128-reg cap -> 4 waves/SIMD.
// Wave w owns: L2 feats [w*16,+16), L3 feats [w*32,+32).
// L1 (tiny, K=4) runs on waves 4..7 only (16 feats each); wave 0 lanes 0..31
// do point staging + next-tile register PREFETCH, which overlaps the L1 phase.
// C/D layout: row (q*4+r) = out-feature, col (nn) = point.
__global__ __launch_bounds__(512, 4) void mlp_kernel(
    const float* __restrict__ pc,
    const float* __restrict__ W1, const float* __restrict__ b1,
    const float* __restrict__ W2, const float* __restrict__ b2,
    const float* __restrict__ W3, const float* __restrict__ b3,
    const int* __restrict__ sid,
    unsigned* __restrict__ pooled,
    float* __restrict__ sums,
    int n, int tiles_per_block) {
  __shared__ __align__(16) __bf16 shF[MT][8];
  __shared__ __align__(16) __bf16 sh1[MT][H1PAD];
  __shared__ __align__(16) __bf16 sh2[MT][H2PAD];
  __shared__ int segt[MT];

  const int t  = threadIdx.x;
  const int w  = t >> 6;         // wave id 0..7
  const int lane = t & 63;
  const int q  = lane >> 4;
  const int nn = lane & 15;

  // ---- persistent weight fragments (A-operand: A[m=nn][k=q*8+j]) ----
  bf16x8 w1f = {};               // L1 on waves 4..7 only, K=32 zero-padded (real K=4)
  float b1r[4] = {0.f, 0.f, 0.f, 0.f};
  if (w >= 4) {
    int wl = w - 4;
    #pragma unroll
    for (int j = 0; j < 8; ++j) {
      int k = q * 8 + j;
      w1f[j] = (k < 4) ? (__bf16)W1[k * H1DIM + wl * 16 + nn] : (__bf16)0.f;
    }
    #pragma unroll
    for (int r = 0; r < 4; ++r) b1r[r] = b1[wl * 16 + q * 4 + r];
  }

  bf16x8 w2f[2];                 // [ks]; wave owns 16 L2 features
  float  b2r[4];
  {
    int m = w * 16 + nn;
    #pragma unroll
    for (int ks = 0; ks < 2; ++ks)
      #pragma unroll
      for (int j = 0; j < 8; ++j)
        w2f[ks][j] = (__bf16)W2[(ks * 32 + q * 8 + j) * H2DIM + m];
    #pragma unroll
    for (int r = 0; r < 4; ++r) b2r[r] = b2[w * 16 + q * 4 + r];
  }

  bf16x8 w3f[2][4];              // [mt][ks]; wave owns 32 latent features
  #pragma unroll
  for (int mt = 0; mt < 2; ++mt) {
    int m = w * 32 + mt * 16 + nn;
    #pragma unroll
    for (int ks = 0; ks < 4; ++ks)
      #pragma unroll
      for (int j = 0; j < 8; ++j)
        w3f[mt][ks][j] = (__bf16)W3[(ks * 32 + q * 8 + j) * LAT + m];
  }

  const f32x4 zero4 = {0.f, 0.f, 0.f, 0.f};
  const bf16x8 zero8 = {};
  const f32x4 neginf4 = {-FLT_MAX, -FLT_MAX, -FLT_MAX, -FLT_MAX};

  f32x4 run[2];                  // running segment max (bias NOT included)
  run[0] = neginf4; run[1] = neginf4;

  // centroid accumulation state (staging threads t<32 only)
  float cx = 0.f, cy = 0.f, cz = 0.f, cc = 0.f;
  int   cseg = -1;

  const int tile0 = blockIdx.x * tiles_per_block;
  int first = tile0 * MT; if (first > n - 1) first = n - 1;
  int s_cur = sid[first];

  // ---- register prefetch of tile 0 (staging threads) ----
  float pf1 = 0.f, pf2 = 0.f, pf3 = 0.f, pfx = 0.f;
  int   pfs = 0; bool pfv = false;
  if (t < MT) {
    int p = tile0 * MT + t;
    pfv = p < n;
    int pcl = pfv ? p : (n - 1);
    const float* pp = pc + (size_t)pcl * 5;
    pf1 = pp[1]; pf2 = pp[2]; pf3 = pp[3]; pfx = pp[4];
    pfs = sid[pcl];
  }

  for (int ti = 0; ti < tiles_per_block; ++ti) {
    const int base = (tile0 + ti) * MT;
    if (base >= n) break;

    // ---- commit prefetched tile to LDS; run centroid accumulation ----
    if (t < MT) {
      bf16x8 v = {};
      v[0] = (__bf16)pfx;   // x first (concat order!)
      v[1] = (__bf16)pf1;
      v[2] = (__bf16)pf2;
      v[3] = (__bf16)pf3;
      *reinterpret_cast<bf16x8*>(&shF[t][0]) = v;
      segt[t] = pfs;
      if (pfv) {
        if (pfs != cseg) {
          if (cc > 0.f) {
            atomicAdd(&sums[cseg * 4 + 0], cx);
            atomicAdd(&sums[cseg * 4 + 1], cy);
            atomicAdd(&sums[cseg * 4 + 2], cz);
            atomicAdd(&sums[cseg * 4 + 3], cc);
          }
          cseg = pfs; cx = 0.f; cy = 0.f; cz = 0.f; cc = 0.f;
        }
        cx += pf1; cy += pf2; cz += pf3; cc += 1.f;
      }
    }
    __syncthreads();

    // ---- issue prefetch for next tile (wave 0; overlaps L1 on waves 4..7) ----
    if (t < MT) {
      int p = (tile0 + ti + 1) * MT + t;
      pfv = p < n;
      int pcl = pfv ? p : (n - 1);
      const float* pp = pc + (size_t)pcl * 5;
      pf1 = pp[1]; pf2 = pp[2]; pf3 = pp[3]; pfx = pp[4];
      pfs = sid[pcl];
    }

    // ---- layer 1 (MFMA, K zero-padded) on waves 4..7 ----
    if (w >= 4) {
      int wl = w - 4;
      f32x4 acc1[2];
      #pragma unroll
      for (int nt = 0; nt < 2; ++nt) {
        bf16x8 ld = *reinterpret_cast<const bf16x8*>(&shF[nt * 16 + nn][0]);
        bf16x8 af = (q == 0) ? ld : zero8;
        acc1[nt] = __builtin_amdgcn_mfma_f32_16x16x32_bf16(w1f, af, zero4, 0, 0, 0);
      }
      #pragma unroll
      for (int nt = 0; nt < 2; ++nt) {
        bf16x4 pk;
        #pragma unroll
        for (int r = 0; r < 4; ++r)
          pk[r] = (__bf16)fmaxf(acc1[nt][r] + b1r[r], 0.f);
        *reinterpret_cast<bf16x4*>(&sh1[nt * 16 + nn][wl * 16 + q * 4]) = pk;
      }
    }
    __syncthreads();

    // ---- layer 2: (32x64) @ (64x128), 16 out-features per wave ----
    {
      f32x4 acc2[2];
      acc2[0] = zero4; acc2[1] = zero4;
      #pragma unroll
      for (int ks = 0; ks < 2; ++ks) {
        bf16x8 bfr[2];
        #pragma unroll
        for (int nt = 0; nt < 2; ++nt)
          bfr[nt] = *reinterpret_cast<const bf16x8*>(&sh1[nt * 16 + nn][ks * 32 + q * 8]);
        #pragma unroll
        for (int nt = 0; nt < 2; ++nt)
          acc2[nt] = __builtin_amdgcn_mfma_f32_16x16x32_bf16(w2f[ks], bfr[nt], acc2[nt], 0, 0, 0);
      }
      #pragma unroll
      for (int nt = 0; nt < 2; ++nt) {
        bf16x4 pk;
        #pragma unroll
        for (int r = 0; r < 4; ++r)
          pk[r] = (__bf16)fmaxf(acc2[nt][r] + b2r[r], 0.f);
        *reinterpret_cast<bf16x4*>(&sh2[nt * 16 + nn][w * 16 + q * 4]) = pk;
      }
    }
    __syncthreads();

    // ---- layer 3: (32x128) @ (128x256), 32 out-features per wave ----
    f32x4 acc3[2][2];
    #pragma unroll
    for (int mt = 0; mt < 2; ++mt)
      #pragma unroll
      for (int nt = 0; nt < 2; ++nt) acc3[mt][nt] = zero4;
    #pragma unroll
    for (int ks = 0; ks < 4; ++ks) {
      bf16x8 bfr[2];
      #pragma unroll
      for (int nt = 0; nt < 2; ++nt)
        bfr[nt] = *reinterpret_cast<const bf16x8*>(&sh2[nt * 16 + nn][ks * 32 + q * 8]);
      #pragma unroll
      for (int mt = 0; mt < 2; ++mt)
        #pragma unroll
        for (int nt = 0; nt < 2; ++nt)
          acc3[mt][nt] = __builtin_amdgcn_mfma_f32_16x16x32_bf16(w3f[mt][ks], bfr[nt], acc3[mt][nt], 0, 0, 0);
    }

    // ---- segment max (sorted ids; block-uniform control) ----
    int smin = segt[0], smax = segt[MT - 1];
    if (smin != s_cur) {           // previous segment ended exactly at tile edge
      flush2(run[0], run[1], s_cur, w, q, nn, b3, pooled);
      run[0] = neginf4; run[1] = neginf4;
      s_cur = smin;
    }
    if (smin == smax) {
      // fast path: whole tile in one segment -> fold into register running max
      #pragma unroll
      for (int mt = 0; mt < 2; ++mt)
        #pragma unroll
        for (int r = 0; r < 4; ++r)
          run[mt][r] = fmaxf(run[mt][r], fmaxf(acc3[mt][0][r], acc3[mt][1][r]));
    } else {
      // slow path: tile crosses >=1 boundary (~255 occurrences total)
      int sg0 = segt[nn], sg1 = segt[16 + nn];
      for (int s = smin; s <= smax; ++s) {
        f32x4 tmp[2];
        #pragma unroll
        for (int mt = 0; mt < 2; ++mt)
          #pragma unroll
          for (int r = 0; r < 4; ++r) {
            float v0 = (sg0 == s) ? acc3[mt][0][r] : -FLT_MAX;
            float v1 = (sg1 == s) ? acc3[mt][1][r] : -FLT_MAX;
            tmp[mt][r] = fmaxf(v0, v1);
          }
        if (s < smax) {
          if (s == s_cur) {
            #pragma unroll
            for (int mt = 0; mt < 2; ++mt)
              #pragma unroll
              for (int r = 0; r < 4; ++r) run[mt][r] = fmaxf(run[mt][r], tmp[mt][r]);
            flush2(run[0], run[1], s, w, q, nn, b3, pooled);
            run[0] = neginf4; run[1] = neginf4;
          } else {
            flush2(tmp[0], tmp[1], s, w, q, nn, b3, pooled);
          }
        } else {
          #pragma unroll
          for (int mt = 0; mt < 2; ++mt)
            #pragma unroll
            for (int r = 0; r < 4; ++r) run[mt][r] = fmaxf(run[mt][r], tmp[mt][r]);
        }
      }
      s_cur = smax;
    }
    __syncthreads();   // protect shF/segt/sh1/sh2 against next iteration's writes
  }
  flush2(run[0], run[1], s_cur, w, q, nn, b3, pooled);

  // final centroid flush
  if (t < MT && cc > 0.f) {
    atomicAdd(&sums[cseg * 4 + 0], cx);
    atomicAdd(&sums[cseg * 4 + 1], cy);
    atomicAdd(&sums[cseg * 4 + 2], cz);
    atomicAdd(&sums[cseg * 4 + 3], cc);
  }
}

// ---------------- head: pooled @ Wf + bf -> softplus, + centroid ----------------
__global__ void final_kernel(const float* __restrict__ sums, const unsigned* __restrict__ pooled,
                             const float* __restrict__ Wf, const float* __restrict__ bfv,
                             float* __restrict__ out) {
  __shared__ float red[4][3];
  int g = blockIdx.x;
  int t = threadIdx.x;   // 256 = LAT
  unsigned u = pooled[g * LAT + t];
  float f = u ? unmapf(u) : 0.f;
  float s0 = f * Wf[t * 3 + 0];
  float s1 = f * Wf[t * 3 + 1];
  float s2 = f * Wf[t * 3 + 2];
  #pragma unroll
  for (int off = 1; off < 64; off <<= 1) {
    s0 += __shfl_xor(s0, off);
    s1 += __shfl_xor(s1, off);
    s2 += __shfl_xor(s2, off);
  }
  int wave = t >> 6;
  if ((t & 63) == 0) { red[wave][0] = s0; red[wave][1] = s1; red[wave][2] = s2; }
  __syncthreads();
  if (t < 3) {
    float acc = bfv[t] + red[0][t] + red[1][t] + red[2][t] + red[3][t];
    float sp  = fmaxf(acc, 0.f) + log1pf(expf(-fabsf(acc)));
    float cnt = fmaxf(sums[g * 4 + 3], 1.f);
    float cen = sums[g * 4 + t] / cnt;
    out[g * 3 + t] = cen + sp;
  }
}

extern "C" void kernel_launch(void* const* d_in, const int* in_sizes, int n_in,
                              void* d_out, int out_size, void* d_ws, size_t ws_size,
                              hipStream_t stream) {
  const float* pc  = (const float*)d_in[0];
  const float* W1  = (const float*)d_in[1];
  const float* b1  = (const float*)d_in[2];
  const float* W2  = (const float*)d_in[3];
  const float* b2  = (const float*)d_in[4];
  const float* W3  = (const float*)d_in[5];
  const float* b3  = (const float*)d_in[6];
  const float* Wf  = (const float*)d_in[7];
  const float* bfv = (const float*)d_in[8];
  const int*   sid = (const int*)d_in[9];
  int n = in_sizes[0] / 5;

  float*    sums   = (float*)d_ws;                         // G*4 fp32
  unsigned* pooled = (unsigned*)((char*)d_ws + 4096);      // G*LAT mapped-uint maxes
  hipMemsetAsync(d_ws, 0, 4096 + (size_t)G * LAT * 4, stream);

  int tiles   = (n + MT - 1) / MT;
  int nblocks = 512;                         // 2 blocks/CU (8 waves each = 16 waves/CU)
  int tpb     = (tiles + nblocks - 1) / nblocks;
  mlp_kernel<<<nblocks, 512, 0, stream>>>(pc, W1, b1, W2, b2, W3, b3, sid, pooled, sums, n, tpb);

  final_kernel<<<G, 256, 0, stream>>>(sums, pooled, Wf, bfv, (float*)d_out);
}